// Round 4
// baseline (541.537 us; speedup 1.0000x reference)
//
#include <hip/hip_runtime.h>
#include <cstdint>
#include <cstddef>

// Problem constants: B=8, C=64, H=W=32 -> N=8192 nodes, K=9 neighbors, OUT=64.
// Batches: k = [1024k,1024(k+1)) for k<=6, batch 7 = [7168,8190], batch 8 = {8191}.
//
// ROUND 4 = PER-KERNEL MEASUREMENT: each kernel body wrapped in an idempotent
// internal rep loop (x32/x6/x8/x16) so every dispatch exceeds the ~45.8us
// fillBuffer ceiling and appears in rocprof top-5. Per-kernel T = dur/reps.
// Known: T_pipeline = 68.4us, harness floor = 60us (R2/R3 A/B).

// ---------------------------------------------------------------------------
// K1: transpose x (8,64,32,32) -> xf[8192][64], sq[n] = sum_c xf[n][c]^2. x32
// ---------------------------------------------------------------------------
__global__ __launch_bounds__(256) void k_transpose_sq(const float* __restrict__ x,
                                                      float* __restrict__ xf,
                                                      float* __restrict__ sq) {
  __shared__ float tile[64][65];
  int blk = blockIdx.x;           // 128 blocks: 8 b x 16 hw-tiles
  int b = blk >> 4;
  int hw0 = (blk & 15) << 6;
  int t = threadIdx.x;
  for (int rep = 0; rep < 32; ++rep) {
    asm volatile("" ::: "memory");
    int lane_hw = t & 63;
    int c_base = t >> 6;            // 0..3
#pragma unroll
    for (int i = 0; i < 16; ++i) {
      int c = c_base + (i << 2);
      tile[c][lane_hw] = x[((b * 64 + c) << 10) + hw0 + lane_hw];
    }
    __syncthreads();
    int c_out = t & 63;
    int hw_base = t >> 6;
#pragma unroll
    for (int i = 0; i < 16; ++i) {
      int hw = hw_base + (i << 2);
      xf[(size_t)(((b << 10) + hw0 + hw) << 6) + c_out] = tile[c_out][hw];
    }
    if (t < 64) {
      float s = 0.f;
#pragma unroll
      for (int c = 0; c < 64; ++c) { float v = tile[c][t]; s += v * v; }
      sq[(b << 10) + hw0 + t] = s;
    }
    __syncthreads();
  }
}

// ---------------------------------------------------------------------------
// K3: distance GEMM. D[i][jj] = sq[i]+sq[j0+jj]-2*dot(xf[i],xf[j0+jj]). x6
// ---------------------------------------------------------------------------
__global__ __launch_bounds__(256) void k_dist(const float* __restrict__ xf,
                                              const float* __restrict__ sq,
                                              float* __restrict__ D) {
  __shared__ float4 As4[2048];    // 32 KB: [q:16][m:128] swizzled
  __shared__ float4 Bs4[2048];    // 32 KB
  int i0 = blockIdx.y << 7;       // 0..8064
  int jj0 = blockIdx.x << 7;      // 0..896
  int s = (i0 >= 7168) ? 7168 : (i0 & ~1023);
  int j0 = s + jj0;
  int t = threadIdx.x;
  int tx = t & 15, ty = t >> 4;

  for (int rep = 0; rep < 6; ++rep) {
    asm volatile("" ::: "memory");
    __syncthreads();
#pragma unroll
    for (int i = 0; i < 8; ++i) {
      int u = t + (i << 8);
      int q = u & 15, m = u >> 4;
      int dst = (q << 7) | (m ^ (q & 7));
      As4[dst] = *(const float4*)&xf[((size_t)(i0 + m) << 6) + (q << 2)];
      Bs4[dst] = *(const float4*)&xf[((size_t)(j0 + m) << 6) + (q << 2)];
    }
    __syncthreads();

    float acc[8][8];
#pragma unroll
    for (int r = 0; r < 8; ++r)
#pragma unroll
      for (int c = 0; c < 8; ++c) acc[r][c] = 0.f;

#pragma unroll 1
    for (int q = 0; q < 16; ++q) {
      int base = q << 7;
      int sw = q & 7;
      float4 a[8], b[8];
#pragma unroll
      for (int r = 0; r < 8; ++r) a[r] = As4[base | ((ty + (r << 4)) ^ sw)];
#pragma unroll
      for (int c = 0; c < 8; ++c) b[c] = Bs4[base | ((tx + (c << 4)) ^ sw)];
#pragma unroll
      for (int r = 0; r < 8; ++r)
#pragma unroll
        for (int c = 0; c < 8; ++c) {
          float v = acc[r][c];
          v = fmaf(a[r].x, b[c].x, v);
          v = fmaf(a[r].y, b[c].y, v);
          v = fmaf(a[r].z, b[c].z, v);
          v = fmaf(a[r].w, b[c].w, v);
          acc[r][c] = v;
        }
    }

    float sqi[8], sqj[8];
#pragma unroll
    for (int r = 0; r < 8; ++r) sqi[r] = sq[i0 + ty + (r << 4)];
#pragma unroll
    for (int c = 0; c < 8; ++c) sqj[c] = sq[j0 + tx + (c << 4)];
#pragma unroll
    for (int r = 0; r < 8; ++r) {
      size_t rowbase = ((size_t)(i0 + ty + (r << 4)) << 10) + jj0 + tx;
#pragma unroll
      for (int c = 0; c < 8; ++c)
        D[rowbase + (c << 4)] = sqi[r] + sqj[c] - 2.f * acc[r][c];
    }
  }
}

// ---------------------------------------------------------------------------
// K4: exact top-9 per row (one wave per row). x8
// ---------------------------------------------------------------------------
__global__ __launch_bounds__(256) void k_select(const float* __restrict__ D,
                                                int* __restrict__ idxO) {
  int t = threadIdx.x;
  int lane = t & 63;
  int i = (blockIdx.x << 2) + (t >> 6);
  for (int rep = 0; rep < 8; ++rep) {
    asm volatile("" ::: "memory");
    if (i == 8191) {                 // singleton batch: neighbor = self
      if (lane == 0) idxO[i * 9] = 8191;
      continue;
    }
    int s = (i >= 7168) ? 7168 : (i & ~1023);
    bool mlast = (i >= 7168);        // rows of batch 7 must exclude j=8191
    const float* drow = D + ((size_t)i << 10);
    unsigned long long cand[16];
#pragma unroll
    for (int q = 0; q < 16; ++q) {
      int jj = lane + (q << 6);
      float d = drow[jj];
      unsigned u = __float_as_uint(d);
      u = (u & 0x80000000u) ? ~u : (u | 0x80000000u);
      unsigned long long key = ((unsigned long long)u << 32) | (unsigned)jj;
      if (mlast && jj == 1023) key = ~0ull;
      cand[q] = key;
    }
#pragma unroll
    for (int kk = 0; kk < 9; ++kk) {
      unsigned long long m = cand[0];
#pragma unroll
      for (int q = 1; q < 16; ++q) m = (cand[q] < m) ? cand[q] : m;
#pragma unroll
      for (int off = 32; off > 0; off >>= 1) {
        unsigned hi = __shfl_xor((unsigned)(m >> 32), off, 64);
        unsigned lo = __shfl_xor((unsigned)(m & 0xffffffffu), off, 64);
        unsigned long long o = ((unsigned long long)hi << 32) | lo;
        m = (o < m) ? o : m;
      }
      if (lane == 0) idxO[i * 9 + kk] = s + (int)(m & 0xffffffffu);
#pragma unroll
      for (int q = 0; q < 16; ++q) if (cand[q] == m) cand[q] = ~0ull;
    }
  }
}

// ---------------------------------------------------------------------------
// K5: mean of neighbors + out = mean@Wl^T + bl + xf@Wr^T. x16
// ---------------------------------------------------------------------------
__global__ __launch_bounds__(256) void k_out(const float* __restrict__ xf,
                                             const int* __restrict__ idxO,
                                             const float* __restrict__ Wl,
                                             const float* __restrict__ bl,
                                             const float* __restrict__ Wr,
                                             float* __restrict__ out) {
  __shared__ float WsL[64][65];
  __shared__ float WsR[64][65];
  int t = threadIdx.x;
  for (int rep = 0; rep < 16; ++rep) {
    asm volatile("" ::: "memory");
    __syncthreads();
#pragma unroll
    for (int i = 0; i < 16; ++i) {
      int lin = t + (i << 8);
      WsL[lin >> 6][lin & 63] = Wl[lin];
      WsR[lin >> 6][lin & 63] = Wr[lin];
    }
    __syncthreads();
    int lane = t & 63;
    float wl[64], wr[64];
#pragma unroll
    for (int c = 0; c < 64; ++c) { wl[c] = WsL[lane][c]; wr[c] = WsR[lane][c]; }
    float bias = bl[lane];
    int wave = t >> 6;
    int n0 = (blockIdx.x << 4) + (wave << 2);   // 4 nodes per wave
    for (int nn = 0; nn < 4; ++nn) {
      int n = n0 + nn;
      int cnt = (n == 8191) ? 1 : 9;            // wave-uniform
      float msum = 0.f;
      for (int k = 0; k < cnt; ++k) {
        int j = idxO[n * 9 + k];                // uniform across wave
        msum += xf[((size_t)j << 6) + lane];    // coalesced gather
      }
      float mean = msum / (float)cnt;           // lane c = feature c
      float xr = xf[((size_t)n << 6) + lane];
      float acc = bias;
#pragma unroll
      for (int c = 0; c < 64; ++c) {
        float mc = __int_as_float(__builtin_amdgcn_readlane(__float_as_int(mean), c));
        float xc = __int_as_float(__builtin_amdgcn_readlane(__float_as_int(xr), c));
        acc += mc * wl[c];
        acc += xc * wr[c];
      }
      out[((size_t)n << 6) + lane] = acc;
    }
  }
}

// ---------------------------------------------------------------------------
extern "C" void kernel_launch(void* const* d_in, const int* in_sizes, int n_in,
                              void* d_out, int out_size, void* d_ws, size_t ws_size,
                              hipStream_t stream) {
  const float* x  = (const float*)d_in[0];   // (8,64,32,32)
  const float* Wl = (const float*)d_in[1];   // (64,64)
  const float* bl = (const float*)d_in[2];   // (64,)
  const float* Wr = (const float*)d_in[3];   // (64,64)
  float* out = (float*)d_out;                // (8192,64)

  char* ws = (char*)d_ws;
  float* xf  = (float*)(ws);                                   // 2,097,152 B
  float* sq  = (float*)(ws + 2097152);                         //    32,768 B
  int*   idx = (int*)  (ws + 2097152 + 32768);                 //   294,912 B
  float* D   = (float*)(ws + 2097152 + 32768 + 294912);        // 33,554,432 B

  k_transpose_sq<<<128, 256, 0, stream>>>(x, xf, sq);
  k_dist<<<dim3(8, 64), 256, 0, stream>>>(xf, sq, D);
  k_select<<<2048, 256, 0, stream>>>(D, idx);
  k_out<<<512, 256, 0, stream>>>(xf, idx, Wl, bl, Wr, out);
}

// Round 5
// 113.039 us; speedup vs baseline: 4.7907x; 4.7907x over previous
//
#include <hip/hip_runtime.h>
#include <cstdint>
#include <cstddef>

// Problem constants: B=8, C=64, H=W=32 -> N=8192 nodes, K=9 neighbors, OUT=64.
// Batches: k = [1024k,1024(k+1)) for k<=6, batch 7 = [7168,8190], batch 8 = {8191}.
//
// R5: harness floor ~60us (fills, fixed). Kernel budget was ~68us:
// T1~2, T3~10-17 (LDS-throughput floor), T4~13-18, T5~11.8, gaps ~8-12.
// This round: k_select rewritten (cached-top2 tournament, slot-encoded keys),
// k_out rewritten (prefetch + fused c-loop, 8 independent FMA chains).

// ---------------------------------------------------------------------------
// K1: transpose x (8,64,32,32) -> xf[8192][64], sq[n] = sum_c xf[n][c]^2
// ---------------------------------------------------------------------------
__global__ __launch_bounds__(256) void k_transpose_sq(const float* __restrict__ x,
                                                      float* __restrict__ xf,
                                                      float* __restrict__ sq) {
  __shared__ float tile[64][65];
  int blk = blockIdx.x;           // 128 blocks: 8 b x 16 hw-tiles
  int b = blk >> 4;
  int hw0 = (blk & 15) << 6;
  int t = threadIdx.x;
  int lane_hw = t & 63;
  int c_base = t >> 6;            // 0..3
#pragma unroll
  for (int i = 0; i < 16; ++i) {
    int c = c_base + (i << 2);
    tile[c][lane_hw] = x[((b * 64 + c) << 10) + hw0 + lane_hw];
  }
  __syncthreads();
  int c_out = t & 63;
  int hw_base = t >> 6;
#pragma unroll
  for (int i = 0; i < 16; ++i) {
    int hw = hw_base + (i << 2);
    xf[(size_t)(((b << 10) + hw0 + hw) << 6) + c_out] = tile[c_out][hw];
  }
  if (t < 64) {
    float s = 0.f;
#pragma unroll
    for (int c = 0; c < 64; ++c) { float v = tile[c][t]; s += v * v; }
    sq[(b << 10) + hw0 + t] = s;
  }
}

// ---------------------------------------------------------------------------
// K3: distance GEMM. D[i][jj] = sq[i]+sq[j0+jj]-2*dot(xf[i],xf[j0+jj]).
// (unchanged from R2 — LDS-throughput floor ~10us; restructure deferred)
// ---------------------------------------------------------------------------
__global__ __launch_bounds__(256) void k_dist(const float* __restrict__ xf,
                                              const float* __restrict__ sq,
                                              float* __restrict__ D) {
  __shared__ float4 As4[2048];    // 32 KB: [q:16][m:128] swizzled
  __shared__ float4 Bs4[2048];    // 32 KB
  int i0 = blockIdx.y << 7;       // 0..8064
  int jj0 = blockIdx.x << 7;      // 0..896
  int s = (i0 >= 7168) ? 7168 : (i0 & ~1023);
  int j0 = s + jj0;
  int t = threadIdx.x;
  int tx = t & 15, ty = t >> 4;

#pragma unroll
  for (int i = 0; i < 8; ++i) {
    int u = t + (i << 8);
    int q = u & 15, m = u >> 4;
    int dst = (q << 7) | (m ^ (q & 7));
    As4[dst] = *(const float4*)&xf[((size_t)(i0 + m) << 6) + (q << 2)];
    Bs4[dst] = *(const float4*)&xf[((size_t)(j0 + m) << 6) + (q << 2)];
  }
  __syncthreads();

  float acc[8][8];
#pragma unroll
  for (int r = 0; r < 8; ++r)
#pragma unroll
    for (int c = 0; c < 8; ++c) acc[r][c] = 0.f;

#pragma unroll 1
  for (int q = 0; q < 16; ++q) {
    int base = q << 7;
    int sw = q & 7;
    float4 a[8], b[8];
#pragma unroll
    for (int r = 0; r < 8; ++r) a[r] = As4[base | ((ty + (r << 4)) ^ sw)];
#pragma unroll
    for (int c = 0; c < 8; ++c) b[c] = Bs4[base | ((tx + (c << 4)) ^ sw)];
#pragma unroll
    for (int r = 0; r < 8; ++r)
#pragma unroll
      for (int c = 0; c < 8; ++c) {
        float v = acc[r][c];
        v = fmaf(a[r].x, b[c].x, v);
        v = fmaf(a[r].y, b[c].y, v);
        v = fmaf(a[r].z, b[c].z, v);
        v = fmaf(a[r].w, b[c].w, v);
        acc[r][c] = v;
      }
  }

  float sqi[8], sqj[8];
#pragma unroll
  for (int r = 0; r < 8; ++r) sqi[r] = sq[i0 + ty + (r << 4)];
#pragma unroll
  for (int c = 0; c < 8; ++c) sqj[c] = sq[j0 + tx + (c << 4)];
#pragma unroll
  for (int r = 0; r < 8; ++r) {
    size_t rowbase = ((size_t)(i0 + ty + (r << 4)) << 10) + jj0 + tx;
#pragma unroll
    for (int c = 0; c < 8; ++c)
      D[rowbase + (c << 4)] = sqi[r] + sqj[c] - 2.f * acc[r][c];
  }
}

// ---------------------------------------------------------------------------
// K4 v2: exact top-9 per row, one wave per row.
// Key = (orderable-dist(u32) << 32) | jj with jj = lane*16 + slot -> keys are
// unique; min = smallest dist, ties -> smallest index (matches lax.top_k).
// Per-lane cached top-2 (m1,m2): common-path round = u64 butterfly + O(1)
// winner update. Full 16-candidate rescan (excluding rmask slots) only when
// the same lane wins a second time (rare; exec-masked, branch-skipped).
// ---------------------------------------------------------------------------
__global__ __launch_bounds__(256) void k_select(const float* __restrict__ D,
                                                int* __restrict__ idxO) {
  int t = threadIdx.x;
  int lane = t & 63;
  int i = (blockIdx.x << 2) + (t >> 6);
  if (i == 8191) {                 // singleton batch: neighbor = self
    if (lane == 0) idxO[i * 9] = 8191;
    return;
  }
  int s = (i >= 7168) ? 7168 : (i & ~1023);
  bool mlast = (i >= 7168);        // rows of batch 7 must exclude j=8191
  const float* drow = D + ((size_t)i << 10);

  unsigned long long cand[16];
#pragma unroll
  for (int q = 0; q < 4; ++q) {
    float4 v = *(const float4*)&drow[(lane << 4) + (q << 2)];
    float vv[4] = {v.x, v.y, v.z, v.w};
#pragma unroll
    for (int e = 0; e < 4; ++e) {
      int slot = (q << 2) + e;
      int jj = (lane << 4) + slot;
      unsigned u = __float_as_uint(vv[e]);
      u = (u & 0x80000000u) ? ~u : (u | 0x80000000u);
      cand[slot] = ((unsigned long long)u << 32) | (unsigned)jj;
    }
  }
  if (mlast && lane == 63) cand[15] = ~0ull;   // jj=1023 == global 8191

  // per-lane top-2: m1 = min, m2 = 2nd min
  unsigned long long m1 = cand[0], m2 = cand[1];
  if (m2 < m1) { unsigned long long tt = m1; m1 = m2; m2 = tt; }
#pragma unroll
  for (int q = 2; q < 16; ++q) {
    unsigned long long c = cand[q];
    unsigned long long lo = (c < m1) ? c : m1;
    unsigned long long hi = (c < m1) ? m1 : c;
    m2 = (hi < m2) ? hi : m2;
    m1 = lo;
  }

  unsigned long long lm = m1;
  unsigned rmask = 0;              // removed slots of THIS lane
  bool stale = false;              // true once m2 has been consumed
#pragma unroll
  for (int kk = 0; kk < 9; ++kk) {
    unsigned long long g = lm;
#pragma unroll
    for (int off = 32; off; off >>= 1) {
      unsigned ghi = __shfl_xor((unsigned)(g >> 32), off, 64);
      unsigned glo = __shfl_xor((unsigned)(g & 0xffffffffu), off, 64);
      unsigned long long o = ((unsigned long long)ghi << 32) | glo;
      g = (o < g) ? o : g;
    }
    if (lane == 0) idxO[i * 9 + kk] = s + (int)(unsigned)(g & 0xffffffffu);

    bool winner = (lm == g);       // exactly one lane (keys unique)
    if (winner) {
      rmask |= 1u << (unsigned)(g & 15u);
      if (!stale) {
        lm = m2;
        stale = true;
      } else {                     // rare: rescan excluding removed slots
        unsigned long long best = ~0ull;
#pragma unroll
        for (int q = 0; q < 16; ++q) {
          bool alive = ((rmask >> q) & 1u) == 0u;
          unsigned long long c = cand[q];
          best = (alive && c < best) ? c : best;
        }
        lm = best;
      }
    }
  }
}

// ---------------------------------------------------------------------------
// K5 v2: mean of neighbors + out = mean@Wl^T + bl + xf@Wr^T.
// Prefetch all 4 nodes' gathers, then ONE fused c-loop with 8 independent
// FMA chains (4 nodes x {L,R}) -> latency hidden by ILP at low occupancy.
// ---------------------------------------------------------------------------
__global__ __launch_bounds__(256) void k_out(const float* __restrict__ xf,
                                             const int* __restrict__ idxO,
                                             const float* __restrict__ Wl,
                                             const float* __restrict__ bl,
                                             const float* __restrict__ Wr,
                                             float* __restrict__ out) {
  __shared__ float WsL[64][65];
  __shared__ float WsR[64][65];
  int t = threadIdx.x;
#pragma unroll
  for (int i = 0; i < 16; ++i) {
    int lin = t + (i << 8);
    WsL[lin >> 6][lin & 63] = Wl[lin];
    WsR[lin >> 6][lin & 63] = Wr[lin];
  }
  __syncthreads();
  int lane = t & 63;
  float wl[64], wr[64];
#pragma unroll
  for (int c = 0; c < 64; ++c) { wl[c] = WsL[lane][c]; wr[c] = WsR[lane][c]; }
  float bias = bl[lane];
  int wave = t >> 6;
  int n0 = (blockIdx.x << 4) + (wave << 2);   // 4 nodes per wave

  float ms[4], xr[4];
#pragma unroll
  for (int nn = 0; nn < 4; ++nn) {
    int n = n0 + nn;
    int cnt = (n == 8191) ? 1 : 9;            // wave-uniform
    float msum = 0.f;
    for (int k = 0; k < cnt; ++k) {
      int j = idxO[n * 9 + k];                // uniform across wave
      msum += xf[((size_t)j << 6) + lane];    // coalesced gather
    }
    ms[nn] = msum / (float)cnt;               // lane c = feature c
    xr[nn] = xf[((size_t)n << 6) + lane];
  }

  float accL[4] = {0.f, 0.f, 0.f, 0.f};
  float accR[4] = {0.f, 0.f, 0.f, 0.f};
#pragma unroll
  for (int c = 0; c < 64; ++c) {
#pragma unroll
    for (int nn = 0; nn < 4; ++nn) {
      float mc = __int_as_float(__builtin_amdgcn_readlane(__float_as_int(ms[nn]), c));
      float xc = __int_as_float(__builtin_amdgcn_readlane(__float_as_int(xr[nn]), c));
      accL[nn] = fmaf(mc, wl[c], accL[nn]);
      accR[nn] = fmaf(xc, wr[c], accR[nn]);
    }
  }
#pragma unroll
  for (int nn = 0; nn < 4; ++nn) {
    int n = n0 + nn;
    out[((size_t)n << 6) + lane] = accL[nn] + accR[nn] + bias;
  }
}

// ---------------------------------------------------------------------------
extern "C" void kernel_launch(void* const* d_in, const int* in_sizes, int n_in,
                              void* d_out, int out_size, void* d_ws, size_t ws_size,
                              hipStream_t stream) {
  const float* x  = (const float*)d_in[0];   // (8,64,32,32)
  const float* Wl = (const float*)d_in[1];   // (64,64)
  const float* bl = (const float*)d_in[2];   // (64,)
  const float* Wr = (const float*)d_in[3];   // (64,64)
  float* out = (float*)d_out;                // (8192,64)

  char* ws = (char*)d_ws;
  float* xf  = (float*)(ws);                                   // 2,097,152 B
  float* sq  = (float*)(ws + 2097152);                         //    32,768 B
  int*   idx = (int*)  (ws + 2097152 + 32768);                 //   294,912 B
  float* D   = (float*)(ws + 2097152 + 32768 + 294912);        // 33,554,432 B

  k_transpose_sq<<<128, 256, 0, stream>>>(x, xf, sq);
  k_dist<<<dim3(8, 64), 256, 0, stream>>>(xf, sq, D);
  k_select<<<2048, 256, 0, stream>>>(D, idx);
  k_out<<<512, 256, 0, stream>>>(xf, idx, Wl, bl, Wr, out);
}

// Round 6
// 107.175 us; speedup vs baseline: 5.0528x; 1.0547x over previous
//
#include <hip/hip_runtime.h>
#include <cstdint>
#include <cstddef>

// Problem: B=8, C=64, H=W=32 -> N=8192 nodes, K=9 neighbors, OUT=64.
// Batches: k = [1024k,1024(k+1)) for k<=6, batch 7 = [7168,8190], batch 8 = {8191}.
// Node g <-> (b = g>>10, hw = g&1023); features x[b][c][hw] (node 8191 -> b=7).
//
// R6: gap-dominated regime (4 launches x ~8us graph-node gap). 4 -> 2 kernels:
//  KA: fused transpose+sq+dist. NCHW is K-major (TN) GEMM layout -> stage
//      x directly into LDS [c][m] planes, no transpose. sq from LDS in-block
//      (same FMA order as dot -> self-dist exactly 0). cx==0 blocks side-write
//      xf for KB's gathers.
//  KB: fused select+out. Tournament winners are wave-uniform -> 9 indices stay
//      in registers; no idx array, no cross-phase sync, no separate k_out.

// ---------------------------------------------------------------------------
// KA: D[i][jj] = sq[i] + sq[j0+jj] - 2*dot(x_f[i], x_f[j0+jj]), jj in [0,1024)
// 128x128 tile per block, 8x8 per thread, K=64 in 2 LDS passes of 32.
// LDS: [c:32][m4:33] float4 planes (pad -> conflict-free staging+frags).
// ---------------------------------------------------------------------------
__global__ __launch_bounds__(256, 2) void k_dist(const float* __restrict__ x,
                                                 float* __restrict__ xf,
                                                 float* __restrict__ D) {
  __shared__ float4 As4[32 * 33];   // 16.9 KB
  __shared__ float4 Bs4[32 * 33];   // 16.9 KB
  __shared__ float sqA[128];
  __shared__ float sqB[128];
  int cx = blockIdx.x;              // 0..7 col-tile
  int i0 = (int)blockIdx.y << 7;    // 0..8064
  int s = (i0 >= 7168) ? 7168 : (i0 & ~1023);
  int j0 = s + (cx << 7);
  const float* xA = x + (((size_t)(i0 >> 10)) << 16) + (i0 & 1023);
  const float* xB = x + (((size_t)(j0 >> 10)) << 16) + (j0 & 1023);
  int t = threadIdx.x;
  int tx = t & 15, ty = t >> 4;     // 16x16 thread grid

  float acc[8][8];
#pragma unroll
  for (int r = 0; r < 8; ++r)
#pragma unroll
    for (int c = 0; c < 8; ++c) acc[r][c] = 0.f;

#pragma unroll 1
  for (int pass = 0; pass < 2; ++pass) {
    if (pass) __syncthreads();      // prev-pass LDS reads done before restage
    int c0 = pass << 5;
    // stage: u = t+256i; c = u>>5 (coalesced 128B rows), m4 = u&31
#pragma unroll
    for (int i = 0; i < 4; ++i) {
      int u = t + (i << 8);
      int c = u >> 5, m4 = u & 31;
      As4[c * 33 + m4] = *(const float4*)&xA[((size_t)(c0 + c) << 10) + (m4 << 2)];
      Bs4[c * 33 + m4] = *(const float4*)&xB[((size_t)(c0 + c) << 10) + (m4 << 2)];
    }
    __syncthreads();
    // sq partial: t<128 -> A-row m=t, else B-row m=t-128; ascending c, fmaf
    // chain == dot chain -> d(i,i) cancels exactly.
    {
      int m = t & 127;
      const float* base = (t < 128) ? (const float*)As4 : (const float*)Bs4;
      float p = 0.f;
#pragma unroll
      for (int c = 0; c < 32; ++c) {
        float v = base[(c * 33 + (m >> 2)) * 4 + (m & 3)];
        p = fmaf(v, v, p);
      }
      float* dst = (t < 128) ? sqA : sqB;
      if (pass == 0) dst[m] = p; else dst[m] += p;
    }
    // xf side-write (cx==0 blocks only): node-major copy for KB's gathers
    if (cx == 0) {
#pragma unroll
      for (int i = 0; i < 16; ++i) {
        int u = t + (i << 8);
        int c = u & 31, m = u >> 5;
        xf[((size_t)(i0 + m) << 6) + c0 + c] =
            ((const float*)As4)[(c * 33 + (m >> 2)) * 4 + (m & 3)];
      }
    }
    // GEMM: per k, 4 ds_read_b128 frags + 64 FMA
#pragma unroll 4
    for (int k = 0; k < 32; ++k) {
      float4 a0 = As4[k * 33 + ty];        // rows 4ty..4ty+3
      float4 a1 = As4[k * 33 + 16 + ty];   // rows 64+4ty..
      float4 b0 = Bs4[k * 33 + tx];        // cols 4tx..4tx+3
      float4 b1 = Bs4[k * 33 + 16 + tx];   // cols 64+4tx..
      float av[8] = {a0.x, a0.y, a0.z, a0.w, a1.x, a1.y, a1.z, a1.w};
      float bv[8] = {b0.x, b0.y, b0.z, b0.w, b1.x, b1.y, b1.z, b1.w};
#pragma unroll
      for (int r = 0; r < 8; ++r)
#pragma unroll
        for (int c = 0; c < 8; ++c)
          acc[r][c] = fmaf(av[r], bv[c], acc[r][c]);
    }
  }
  __syncthreads();                  // sqA/sqB complete before epilogue reads

  int rloc[8], cloc[8];
#pragma unroll
  for (int r = 0; r < 4; ++r) { rloc[r] = (ty << 2) + r; rloc[4 + r] = 64 + (ty << 2) + r; }
#pragma unroll
  for (int c = 0; c < 4; ++c) { cloc[c] = (tx << 2) + c; cloc[4 + c] = 64 + (tx << 2) + c; }
  float sqi[8], sqj[8];
#pragma unroll
  for (int r = 0; r < 8; ++r) sqi[r] = sqA[rloc[r]];
#pragma unroll
  for (int c = 0; c < 8; ++c) sqj[c] = sqB[cloc[c]];
#pragma unroll
  for (int r = 0; r < 8; ++r) {
    size_t rb = ((size_t)(i0 + rloc[r]) << 10) + (cx << 7);
    float4 o0, o1;
    o0.x = sqi[r] + sqj[0] - 2.f * acc[r][0];
    o0.y = sqi[r] + sqj[1] - 2.f * acc[r][1];
    o0.z = sqi[r] + sqj[2] - 2.f * acc[r][2];
    o0.w = sqi[r] + sqj[3] - 2.f * acc[r][3];
    o1.x = sqi[r] + sqj[4] - 2.f * acc[r][4];
    o1.y = sqi[r] + sqj[5] - 2.f * acc[r][5];
    o1.z = sqi[r] + sqj[6] - 2.f * acc[r][6];
    o1.w = sqi[r] + sqj[7] - 2.f * acc[r][7];
    *(float4*)&D[rb + (tx << 2)] = o0;
    *(float4*)&D[rb + 64 + (tx << 2)] = o1;
  }
}

// ---------------------------------------------------------------------------
// KB: fused top-9 select + SAGE output. 512 blocks x 16 rows; wave w owns
// rows n0+4w..n0+4w+3. Key = (orderable-dist << 32) | jj (jj = lane*16+slot)
// -> unique keys, smaller-index tie-break (matches lax.top_k). Winners are
// wave-uniform after the butterfly -> kept in registers across phases.
// ---------------------------------------------------------------------------
__global__ __launch_bounds__(256, 2) void k_selout(const float* __restrict__ D,
                                                   const float* __restrict__ xf,
                                                   const float* __restrict__ Wl,
                                                   const float* __restrict__ bl,
                                                   const float* __restrict__ Wr,
                                                   float* __restrict__ out) {
  __shared__ float WsL[64][65];
  __shared__ float WsR[64][65];
  int t = threadIdx.x;
#pragma unroll
  for (int i = 0; i < 16; ++i) {
    int lin = t + (i << 8);
    WsL[lin >> 6][lin & 63] = Wl[lin];
    WsR[lin >> 6][lin & 63] = Wr[lin];
  }
  __syncthreads();
  int lane = t & 63;
  float wl[64], wr[64];
#pragma unroll
  for (int c = 0; c < 64; ++c) { wl[c] = WsL[lane][c]; wr[c] = WsR[lane][c]; }
  float bias = bl[lane];
  int w = t >> 6;
  int n0 = ((int)blockIdx.x << 4) + (w << 2);

  unsigned j9[4][9];                // wave-uniform global neighbor indices
#pragma unroll
  for (int r = 0; r < 4; ++r) {
    int n = n0 + r;
    if (n == 8191) { j9[r][0] = 8191u; continue; }   // singleton batch: self
    int s = (n >= 7168) ? 7168 : (n & ~1023);
    bool mlast = (n >= 7168);       // batch-7 rows exclude jj=1023 (node 8191)
    const float* drow = D + ((size_t)n << 10);
    unsigned long long cand[16];
#pragma unroll
    for (int q = 0; q < 4; ++q) {
      float4 v = *(const float4*)&drow[(lane << 4) + (q << 2)];
      float vv[4] = {v.x, v.y, v.z, v.w};
#pragma unroll
      for (int e = 0; e < 4; ++e) {
        int slot = (q << 2) + e;
        unsigned u = __float_as_uint(vv[e]);
        u = (u & 0x80000000u) ? ~u : (u | 0x80000000u);
        cand[slot] = ((unsigned long long)u << 32) | (unsigned)((lane << 4) + slot);
      }
    }
    if (mlast && lane == 63) cand[15] = ~0ull;
    // per-lane top-2 cache
    unsigned long long m1 = cand[0], m2 = cand[1];
    if (m2 < m1) { unsigned long long tt = m1; m1 = m2; m2 = tt; }
#pragma unroll
    for (int q = 2; q < 16; ++q) {
      unsigned long long c = cand[q];
      unsigned long long lo = (c < m1) ? c : m1;
      unsigned long long hi = (c < m1) ? m1 : c;
      m2 = (hi < m2) ? hi : m2;
      m1 = lo;
    }
    unsigned long long lm = m1;
    unsigned rmask = 0;
    bool stale = false;
#pragma unroll
    for (int kk = 0; kk < 9; ++kk) {
      unsigned long long g = lm;
#pragma unroll
      for (int off = 32; off; off >>= 1) {
        unsigned ghi = __shfl_xor((unsigned)(g >> 32), off, 64);
        unsigned glo = __shfl_xor((unsigned)g, off, 64);
        unsigned long long o = ((unsigned long long)ghi << 32) | glo;
        g = (o < g) ? o : g;
      }
      j9[r][kk] = (unsigned)s + ((unsigned)g & 1023u);
      if (lm == g) {                // exactly one winner lane (unique keys)
        rmask |= 1u << (unsigned)(g & 15u);
        if (!stale) { lm = m2; stale = true; }
        else {                      // rare: rescan excluding removed slots
          unsigned long long best = ~0ull;
#pragma unroll
          for (int q = 0; q < 16; ++q) {
            bool alive = ((rmask >> q) & 1u) == 0u;
            unsigned long long c = cand[q];
            best = (alive && c < best) ? c : best;
          }
          lm = best;
        }
      }
    }
  }

  // out phase: gathers (uniform index -> coalesced 256B rows), fused FMA
  float ms[4], xr[4];
#pragma unroll
  for (int r = 0; r < 4; ++r) {
    int n = n0 + r;
    int cnt = (n == 8191) ? 1 : 9;  // wave-uniform
    float msum = 0.f;
    for (int k = 0; k < cnt; ++k)
      msum += xf[((size_t)j9[r][k] << 6) + lane];
    ms[r] = msum / (float)cnt;      // lane c = feature c
    xr[r] = xf[((size_t)n << 6) + lane];
  }
  float accL[4] = {0.f, 0.f, 0.f, 0.f};
  float accR[4] = {0.f, 0.f, 0.f, 0.f};
#pragma unroll
  for (int c = 0; c < 64; ++c) {
#pragma unroll
    for (int r = 0; r < 4; ++r) {
      float mc = __int_as_float(__builtin_amdgcn_readlane(__float_as_int(ms[r]), c));
      float xc = __int_as_float(__builtin_amdgcn_readlane(__float_as_int(xr[r]), c));
      accL[r] = fmaf(mc, wl[c], accL[r]);
      accR[r] = fmaf(xc, wr[c], accR[r]);
    }
  }
#pragma unroll
  for (int r = 0; r < 4; ++r)
    out[((size_t)(n0 + r) << 6) + lane] = accL[r] + accR[r] + bias;
}

// ---------------------------------------------------------------------------
extern "C" void kernel_launch(void* const* d_in, const int* in_sizes, int n_in,
                              void* d_out, int out_size, void* d_ws, size_t ws_size,
                              hipStream_t stream) {
  const float* x  = (const float*)d_in[0];   // (8,64,32,32)
  const float* Wl = (const float*)d_in[1];   // (64,64)
  const float* bl = (const float*)d_in[2];   // (64,)
  const float* Wr = (const float*)d_in[3];   // (64,64)
  float* out = (float*)d_out;                // (8192,64)

  char* ws = (char*)d_ws;
  float* xf = (float*)(ws);                  //  2,097,152 B (node-major copy)
  float* D  = (float*)(ws + 2097152);        // 33,554,432 B (distances)

  k_dist<<<dim3(8, 64), 256, 0, stream>>>(x, xf, D);
  k_selout<<<512, 256, 0, stream>>>(D, xf, Wl, bl, Wr, out);
}